// Round 1
// baseline (628.054 us; speedup 1.0000x reference)
//
#include <hip/hip_runtime.h>
#include <math.h>

// PatchCore-DINOv2 anomaly score.
// Pipeline: prep (normalize) -> score (bf16 MFMA GEMM + per-tile min, exact msq)
//          -> refine (exact f32 on candidate tiles, eps-bounded) -> final (max/global/combine).
// bf16 error bound |d(d^2)| <= ~0.18 << tile-min order-stat gap (~7); eps=1.0 -> exact result.

#define D 384
#define TQ 128
#define TN 128
#define NSTEPS 12   // 384/32
#define LROW 40     // LDS row stride in bf16 elems (80B): pad 32->40 kills bank conflicts

typedef __attribute__((ext_vector_type(8))) short short8v;
typedef __attribute__((ext_vector_type(4))) float f32x4;

static __device__ __forceinline__ unsigned short f2bf(float f) {
  unsigned u = __float_as_uint(f);
  unsigned r = 0x7FFFu + ((u >> 16) & 1u);   // round-to-nearest-even
  return (unsigned short)((u + r) >> 16);
}
static __device__ __forceinline__ unsigned pack2(float lo, float hi) {
  return (unsigned)f2bf(lo) | ((unsigned)f2bf(hi) << 16);
}

// ---------------- prep: L2-normalize patches + globals, emit f32/bf16/psq ----------------
__global__ void prep_kernel(const float* __restrict__ patches,
                            const float* __restrict__ globals_x,
                            float* __restrict__ pf32,
                            unsigned short* __restrict__ pbf,
                            float* __restrict__ psq,
                            float* __restrict__ gf32,
                            float* __restrict__ gsq,
                            int Q) {
  const int row = blockIdx.x;
  const int lane = threadIdx.x;  // 64 threads = 1 wave
  const float* src = (row < Q) ? (patches + (size_t)row * D)
                               : (globals_x + (size_t)(row - Q) * D);
  float v[6];
  float ss = 0.f;
#pragma unroll
  for (int j = 0; j < 6; ++j) { v[j] = src[lane + 64 * j]; ss += v[j] * v[j]; }
#pragma unroll
  for (int d = 1; d < 64; d <<= 1) ss += __shfl_xor(ss, d);
  const float inv = 1.f / (sqrtf(ss) + 1e-12f);   // x / (||x|| + EPS), as reference
  float pn[6]; float ps = 0.f;
#pragma unroll
  for (int j = 0; j < 6; ++j) { pn[j] = v[j] * inv; ps += pn[j] * pn[j]; }
#pragma unroll
  for (int d = 1; d < 64; d <<= 1) ps += __shfl_xor(ps, d);
  if (row < Q) {
#pragma unroll
    for (int j = 0; j < 6; ++j) {
      pf32[(size_t)row * D + lane + 64 * j] = pn[j];
      pbf[(size_t)row * D + lane + 64 * j] = f2bf(pn[j]);
    }
    if (lane == 0) psq[row] = ps;
  } else {
    const int b = row - Q;
#pragma unroll
    for (int j = 0; j < 6; ++j) gf32[(size_t)b * D + lane + 64 * j] = pn[j];
    if (lane == 0) gsq[b] = ps;
  }
}

// ---------------- score: bf16 MFMA, C[q,n]=p.m; tilemin[tile][q] = min_n (msq - 2*dot) ----------------
__global__ __launch_bounds__(256) void score_kernel(
    const float* __restrict__ mbl,
    const unsigned short* __restrict__ pbf,
    float* __restrict__ tilemin,   // [NTILES][Q]
    int Q, int N, int NTILES) {
  __shared__ alignas(16) unsigned short lA[TQ * LROW];
  __shared__ alignas(16) unsigned short lB[TN * LROW];
  __shared__ float msq_tile[TN];
  __shared__ float partial[4][64];

  const int tid = threadIdx.x;
  const int lane = tid & 63;
  const int wid = tid >> 6;
  const int wq = wid >> 1;
  const int wn = wid & 1;
  const int qbase = blockIdx.x * TQ;
  const int nt = blockIdx.y;
  const int nbase = nt * TN;

  // staging: 2 threads per row, 16 elems each
  const int srow = tid >> 1;
  const int sseg = (tid & 1) << 4;
  const unsigned short* aptr = pbf + (size_t)(qbase + srow) * D + sseg;
  const int gn = nbase + srow;
  const bool nvalid = gn < N;
  const float* bptr = mbl + (size_t)(nvalid ? gn : 0) * D + sseg;
  unsigned short* aw = &lA[srow * LROW + sseg];
  unsigned short* bw = &lB[srow * LROW + sseg];

  // fragment read addresses (16x16x32: row = lane&15, k-block = lane>>4)
  const int fr = lane & 15;
  const int kb = (lane >> 4) << 3;
  const unsigned short* ard = &lA[(wq * 64 + fr) * LROW + kb];
  const unsigned short* brd = &lB[(wn * 64 + fr) * LROW + kb];

  f32x4 acc[4][4];
#pragma unroll
  for (int i = 0; i < 4; ++i)
#pragma unroll
    for (int j = 0; j < 4; ++j) acc[i][j] = (f32x4){0.f, 0.f, 0.f, 0.f};
  float msq_part = 0.f;

  for (int ks = 0; ks < NSTEPS; ++ks) {
    const int k0 = ks << 5;
    // A: 16 bf16 (32B) straight copy
    uint4 a0 = *(const uint4*)(aptr + k0);
    uint4 a1 = *(const uint4*)(aptr + k0 + 8);
    // B: 16 f32 -> bf16 convert, fold msq accumulation
    float4 f0, f1, f2, f3;
    if (nvalid) {
      const float4* bp = (const float4*)(bptr + k0);
      f0 = bp[0]; f1 = bp[1]; f2 = bp[2]; f3 = bp[3];
    } else {
      f0 = f1 = f2 = f3 = (float4){0.f, 0.f, 0.f, 0.f};
    }
    msq_part += f0.x*f0.x + f0.y*f0.y + f0.z*f0.z + f0.w*f0.w
              + f1.x*f1.x + f1.y*f1.y + f1.z*f1.z + f1.w*f1.w
              + f2.x*f2.x + f2.y*f2.y + f2.z*f2.z + f2.w*f2.w
              + f3.x*f3.x + f3.y*f3.y + f3.z*f3.z + f3.w*f3.w;
    uint4 w0 = { pack2(f0.x,f0.y), pack2(f0.z,f0.w), pack2(f1.x,f1.y), pack2(f1.z,f1.w) };
    uint4 w1 = { pack2(f2.x,f2.y), pack2(f2.z,f2.w), pack2(f3.x,f3.y), pack2(f3.z,f3.w) };
    *(uint4*)aw       = a0;
    *(uint4*)(aw + 8) = a1;
    *(uint4*)bw       = w0;
    *(uint4*)(bw + 8) = w1;
    __syncthreads();

    short8v a[4], b[4];
#pragma unroll
    for (int mf = 0; mf < 4; ++mf) a[mf] = *(const short8v*)(ard + mf * 16 * LROW);
#pragma unroll
    for (int nf = 0; nf < 4; ++nf) b[nf] = *(const short8v*)(brd + nf * 16 * LROW);
#pragma unroll
    for (int mf = 0; mf < 4; ++mf)
#pragma unroll
      for (int nf = 0; nf < 4; ++nf)
        acc[mf][nf] = __builtin_amdgcn_mfma_f32_16x16x32_bf16(a[mf], b[nf], acc[mf][nf], 0, 0, 0);
    __syncthreads();
  }

  // exact f32 msq per bank row (from the staged f32 reads; invalid rows -> +inf)
  const float msq_full = msq_part + __shfl_xor(msq_part, 1);
  if ((tid & 1) == 0) msq_tile[srow] = nvalid ? msq_full : 1e30f;
  __syncthreads();

  float msqv[4];
#pragma unroll
  for (int nf = 0; nf < 4; ++nf) msqv[nf] = msq_tile[wn * 64 + nf * 16 + fr];
  float rmin[4][4];
#pragma unroll
  for (int mf = 0; mf < 4; ++mf)
#pragma unroll
    for (int j = 0; j < 4; ++j) {
      float m0 = msqv[0] - 2.f * acc[mf][0][j];
      float m1 = msqv[1] - 2.f * acc[mf][1][j];
      float m2 = msqv[2] - 2.f * acc[mf][2][j];
      float m3 = msqv[3] - 2.f * acc[mf][3][j];
      rmin[mf][j] = fminf(fminf(m0, m1), fminf(m2, m3));
    }
#pragma unroll
  for (int d = 1; d < 16; d <<= 1)
#pragma unroll
    for (int mf = 0; mf < 4; ++mf)
#pragma unroll
      for (int j = 0; j < 4; ++j)
        rmin[mf][j] = fminf(rmin[mf][j], __shfl_xor(rmin[mf][j], d));
  if (fr == 0) {
    const int g = lane >> 4;
#pragma unroll
    for (int mf = 0; mf < 4; ++mf)
#pragma unroll
      for (int j = 0; j < 4; ++j)
        partial[wid][mf * 16 + g * 4 + j] = rmin[mf][j];
  }
  __syncthreads();
  if (tid < TQ) {
    const int wqq = tid >> 6;
    const int r = tid & 63;
    const float m = fminf(partial[wqq * 2][r], partial[wqq * 2 + 1][r]);
    tilemin[(size_t)nt * Q + qbase + tid] = m;   // coalesced store
  }
}

// ---------------- block min helper (blockDim == 256) ----------------
__device__ __forceinline__ float block_min(float v, float* red) {
#pragma unroll
  for (int d = 1; d < 64; d <<= 1) v = fminf(v, __shfl_xor(v, d));
  if ((threadIdx.x & 63) == 0) red[threadIdx.x >> 6] = v;
  __syncthreads();
  const float r = fminf(fminf(red[0], red[1]), fminf(red[2], red[3]));
  __syncthreads();
  return r;
}

// ---------------- refine: exact f32 distance on candidate tiles ----------------
__global__ __launch_bounds__(256) void refine_kernel(
    const float* __restrict__ mbl,
    const float* __restrict__ pf32,
    const float* __restrict__ psq,
    const float* __restrict__ tilemin,
    float* __restrict__ dmin,
    int Q, int N, int NTILES) {
  __shared__ float red[4];
  const int q = blockIdx.x;
  const int tid = threadIdx.x;
  float m = 1e30f;
  for (int t = tid; t < NTILES; t += 256) m = fminf(m, tilemin[(size_t)t * Q + q]);
  m = block_min(m, red);
  const float thr = m + 1.0f;   // >> 2 * worst-case bf16 error (~0.36)
  const float* prow = pf32 + (size_t)q * D;
  float best = 1e30f;
  for (int t = 0; t < NTILES; ++t) {
    if (tilemin[(size_t)t * Q + q] <= thr) {   // uniform branch across the block
      const int n = t * TN + tid;
      if (tid < TN && n < N) {
        const float* mr = mbl + (size_t)n * D;
        float dot = 0.f, ms = 0.f;
#pragma unroll 4
        for (int k = 0; k < D; k += 4) {
          float4 a = *(const float4*)(mr + k);
          float4 p = *(const float4*)(prow + k);
          dot += a.x*p.x + a.y*p.y + a.z*p.z + a.w*p.w;
          ms  += a.x*a.x + a.y*a.y + a.z*a.z + a.w*a.w;
        }
        best = fminf(best, ms - 2.f * dot);
      }
    }
  }
  best = block_min(best, red);
  if (tid == 0) dmin[q] = sqrtf(fmaxf(psq[q] + best, 0.f));
}

// ---------------- final: local max over patches + global branch + combine ----------------
__global__ __launch_bounds__(256) void final_kernel(
    const float* __restrict__ mbg,
    const float* __restrict__ gf32,
    const float* __restrict__ gsq,
    const float* __restrict__ dmin,
    float* __restrict__ out,
    int M, int P) {
  __shared__ float red[4];
  const int b = blockIdx.x;
  const int tid = threadIdx.x;
  float v = (tid < P) ? dmin[(size_t)b * P + tid] : -1e30f;
#pragma unroll
  for (int d = 1; d < 64; d <<= 1) v = fmaxf(v, __shfl_xor(v, d));
  if ((tid & 63) == 0) red[tid >> 6] = v;
  __syncthreads();
  const float local = fmaxf(fmaxf(red[0], red[1]), fmaxf(red[2], red[3]));
  __syncthreads();

  const float* g = gf32 + (size_t)b * D;
  float gm = 1e30f;
  for (int m0 = tid; m0 < M; m0 += 256) {
    const float* mr = mbg + (size_t)m0 * D;
    float dot = 0.f, ms = 0.f;
#pragma unroll 4
    for (int k = 0; k < D; k += 4) {
      float4 a = *(const float4*)(mr + k);
      float4 p = *(const float4*)(g + k);
      dot += a.x*p.x + a.y*p.y + a.z*p.z + a.w*p.w;
      ms  += a.x*a.x + a.y*a.y + a.z*a.z + a.w*a.w;
    }
    gm = fminf(gm, sqrtf(fmaxf(gsq[b] + ms - 2.f * dot, 0.f)));
  }
  gm = block_min(gm, red);
  if (tid == 0) out[b] = 0.7f * local + 0.3f * gm;
}

extern "C" void kernel_launch(void* const* d_in, const int* in_sizes, int n_in,
                              void* d_out, int out_size, void* d_ws, size_t ws_size,
                              hipStream_t stream) {
  const float* patches   = (const float*)d_in[0];
  const float* globals_x = (const float*)d_in[1];
  const float* mbl       = (const float*)d_in[2];
  const float* mbg       = (const float*)d_in[3];
  float* out = (float*)d_out;

  const int Q = in_sizes[0] / D;          // 1024
  const int B = in_sizes[1] / D;          // 4
  const int N = in_sizes[2] / D;          // 100000
  const int M = in_sizes[3] / D;          // 2000
  const int P = Q / B;                    // 256
  const int NTILES = (N + TN - 1) / TN;   // 782
  const int QT = Q / TQ;                  // 8

  char* w = (char*)d_ws;
  auto alloc = [&](size_t bytes) {
    char* p = w;
    w += (bytes + 255) & ~(size_t)255;
    return p;
  };
  float*          pf32    = (float*)alloc((size_t)Q * D * sizeof(float));
  unsigned short* pbf     = (unsigned short*)alloc((size_t)Q * D * sizeof(unsigned short));
  float*          psq     = (float*)alloc((size_t)Q * sizeof(float));
  float*          gf32    = (float*)alloc((size_t)B * D * sizeof(float));
  float*          gsqp    = (float*)alloc((size_t)B * sizeof(float));
  float*          tilemin = (float*)alloc((size_t)NTILES * Q * sizeof(float));
  float*          dmin    = (float*)alloc((size_t)Q * sizeof(float));

  prep_kernel<<<Q + B, 64, 0, stream>>>(patches, globals_x, pf32, pbf, psq, gf32, gsqp, Q);
  score_kernel<<<dim3(QT, NTILES), 256, 0, stream>>>(mbl, pbf, tilemin, Q, N, NTILES);
  refine_kernel<<<Q, 256, 0, stream>>>(mbl, pf32, psq, tilemin, dmin, Q, N, NTILES);
  final_kernel<<<B, 256, 0, stream>>>(mbg, gf32, gsqp, dmin, out, M, P);
}